// Round 1
// baseline (126.583 us; speedup 1.0000x reference)
//
#include <hip/hip_runtime.h>

#define RR 4
#define NS 17
#define BB 4
#define CC 128
#define HH 96
#define WW 160
#define HWSZ (HH * WW)

// Block: 32 (w) x 8 (h-groups); each thread owns TH=2 rows at one w.
// Block pixel tile: 16 rows x 32 cols. LDS tgt tile: 24 x 40 (halo R=4 each side).
#define TW 32
#define HTILE 16
#define TH 2
#define TROWS (HTILE + 2 * RR)  // 24
#define TCOLS (TW + 2 * RR)     // 40
#define TILE_N (TROWS * TCOLS)  // 960
#define CCHUNK 32               // channels per block
#define NCHUNK (CC / CCHUNK)    // 4

__global__ __launch_bounds__(256, 4)
void cost_volume_kernel(const float* __restrict__ src,
                        const float* __restrict__ tgt,
                        float* __restrict__ out) {
    __shared__ float tile[TROWS][TCOLS];  // 3840 B

    const int x   = threadIdx.x;            // 0..31
    const int hg  = threadIdx.y;            // 0..7
    const int tid = hg * TW + x;            // 0..255

    const int w0 = blockIdx.x * TW;         // 0..128 step 32 (exact: 160=5*32)
    const int h0 = blockIdx.y * HTILE;      // 0..80
    const int b  = blockIdx.z & 3;
    const int c0 = (blockIdx.z >> 2) * CCHUNK;

    const int w  = w0 + x;                  // always < WW
    const int hb = h0 + hg * TH;            // thread's first pixel row

    float acc[TH][NS];
#pragma unroll
    for (int i = 0; i < TH; ++i)
#pragma unroll
        for (int s = 0; s < NS; ++s) acc[i][s] = 0.f;

    const float* tgt_b = tgt + (size_t)(b * CC) * HWSZ;
    const float* src_b = src + (size_t)(b * CC) * HWSZ;

    // --- software-pipelined staging: fetch channel tile into regs, then LDS ---
    float pre[4];
    float spre[TH];

    auto fetch_tile = [&](int c, float vals[4]) {
        const float* t = tgt_b + (size_t)c * HWSZ;
#pragma unroll
        for (int k = 0; k < 4; ++k) {
            int idx = tid + k * 256;
            float v = 0.f;
            if (idx < TILE_N) {
                int r   = idx / TCOLS;
                int col = idx - r * TCOLS;
                int gr  = h0 - RR + r;
                int gc  = w0 - RR + col;
                if (gr >= 0 && gr < HH && gc >= 0 && gc < WW)
                    v = t[gr * WW + gc];
            }
            vals[k] = v;
        }
    };
    auto fetch_src = [&](int c, float vals[TH]) {
        const float* sp = src_b + (size_t)c * HWSZ + hb * WW + w;
#pragma unroll
        for (int i = 0; i < TH; ++i) vals[i] = sp[i * WW];
    };

    fetch_tile(c0, pre);
    fetch_src(c0, spre);

    for (int cc = 0; cc < CCHUNK; ++cc) {
        // write staged regs to LDS
#pragma unroll
        for (int k = 0; k < 4; ++k) {
            int idx = tid + k * 256;
            if (idx < TILE_N) ((float*)tile)[idx] = pre[k];
        }
        float sv[TH];
#pragma unroll
        for (int i = 0; i < TH; ++i) sv[i] = spre[i];
        __syncthreads();

        // prefetch next channel while computing this one
        if (cc + 1 < CCHUNK) {
            fetch_tile(c0 + cc + 1, pre);
            fetch_src(c0 + cc + 1, spre);
        }

        // compute: 17 LDS reads + 17 FMAs per pixel
#pragma unroll
        for (int i = 0; i < TH; ++i) {
            const int r   = RR + hg * TH + i;  // tile row of this pixel
            const int col = RR + x;
            acc[i][0] = fmaf(sv[i], tile[r][col], acc[i][0]);
#pragma unroll
            for (int off = 1; off <= RR; ++off) {
                float up    = tile[r - off][col];
                float down  = tile[r + off][col];
                float left  = tile[r][col - off];
                float right = tile[r][col + off];
                acc[i][4 * off - 3] = fmaf(sv[i], up,    acc[i][4 * off - 3]);
                acc[i][4 * off - 2] = fmaf(sv[i], down,  acc[i][4 * off - 2]);
                acc[i][4 * off - 1] = fmaf(sv[i], left,  acc[i][4 * off - 1]);
                acc[i][4 * off    ] = fmaf(sv[i], right, acc[i][4 * off    ]);
            }
        }
        __syncthreads();
    }

    // epilogue: atomic accumulate (4 channel-chunks race per output)
#pragma unroll
    for (int i = 0; i < TH; ++i) {
        const int h = hb + i;
#pragma unroll
        for (int s = 0; s < NS; ++s) {
            atomicAdd(out + (((size_t)b * NS + s) * HH + h) * WW + w, acc[i][s]);
        }
    }
}

extern "C" void kernel_launch(void* const* d_in, const int* in_sizes, int n_in,
                              void* d_out, int out_size, void* d_ws, size_t ws_size,
                              hipStream_t stream) {
    const float* src = (const float*)d_in[0];
    const float* tgt = (const float*)d_in[1];
    float* out = (float*)d_out;

    // d_out is poisoned 0xAA before every launch; we accumulate atomically -> zero it
    hipMemsetAsync(out, 0, (size_t)out_size * sizeof(float), stream);

    dim3 block(TW, 8, 1);                    // 256 threads
    dim3 grid(WW / TW, HH / HTILE, BB * NCHUNK);  // (5, 6, 16) = 480 blocks
    cost_volume_kernel<<<grid, block, 0, stream>>>(src, tgt, out);
}